// Round 1
// baseline (368.254 us; speedup 1.0000x reference)
//
#include <hip/hip_runtime.h>
#include <hip/hip_bf16.h>

typedef __attribute__((ext_vector_type(8))) short bf16x8;
typedef __attribute__((ext_vector_type(4))) float f32x4;
typedef __attribute__((ext_vector_type(8))) unsigned short u16x8;
typedef __attribute__((ext_vector_type(4))) unsigned short u16x4;

#define BN_EPS 1e-5f

__device__ __forceinline__ unsigned short f2bf(float f) {
  unsigned int u = __float_as_uint(f);
  unsigned int r = u + 0x7FFFu + ((u >> 16) & 1u);
  return (unsigned short)(r >> 16);
}
__device__ __forceinline__ float bf2f(unsigned short u) {
  union { float f; unsigned int i; } v; v.i = ((unsigned int)u) << 16; return v.f;
}

// async global->LDS, 16B per lane. LDS dest = wave-uniform base + lane*16.
__device__ __forceinline__ void async_ld16(const unsigned short* g, unsigned short* l) {
  __builtin_amdgcn_global_load_lds(
      (const __attribute__((address_space(1))) void*)g,
      (__attribute__((address_space(3))) void*)l, 16, 0, 0);
}

// ---------------------------------------------------------------------------
// K0: fold BN params -> bias1[256], W2f[9*256] (scale folded), bias2[9]
__global__ __launch_bounds__(256) void params_kernel(
    const float* __restrict__ g1, const float* __restrict__ b1,
    const float* __restrict__ m1, const float* __restrict__ v1,
    const float* __restrict__ W2, const float* __restrict__ g2,
    const float* __restrict__ b2, const float* __restrict__ m2,
    const float* __restrict__ v2,
    float* __restrict__ bias1, float* __restrict__ W2f, float* __restrict__ bias2)
{
  int t = threadIdx.x;
  {
    float s = g1[t] * rsqrtf(v1[t] + BN_EPS);
    bias1[t] = b1[t] - m1[t] * s;
  }
  for (int i = t; i < 2304; i += 256) {
    int j = i >> 8;
    float s2 = g2[j] * rsqrtf(v2[j] + BN_EPS);
    W2f[i] = W2[i] * s2;
  }
  if (t < 9) {
    float s2 = g2[t] * rsqrtf(v2[t] + BN_EPS);
    bias2[t] = b2[t] - m2[t] * s2;
  }
}

// ---------------------------------------------------------------------------
// K1: fold scale1 into W1, quantize bf16, transpose to Bt[o][tap*256 + i]
__global__ __launch_bounds__(256) void fold_w1_kernel(
    const float* __restrict__ W1, const float* __restrict__ g1,
    const float* __restrict__ v1, unsigned short* __restrict__ Bt)
{
  int o = blockIdx.x;           // 0..255
  int t = threadIdx.x;          // = input channel i
  float s = g1[o] * rsqrtf(v1[o] + BN_EPS);
  const float* src = W1 + (size_t)o * 2304 + (size_t)t * 9;
  float wv[9];
  #pragma unroll
  for (int tap = 0; tap < 9; ++tap) wv[tap] = src[tap] * s;
  unsigned short* dst = Bt + (size_t)o * 2304 + t;
  #pragma unroll
  for (int tap = 0; tap < 9; ++tap) dst[tap * 256] = f2bf(wv[tap]);
}

// ---------------------------------------------------------------------------
// K1b: zero only the pad border of yTp
__global__ __launch_bounds__(256) void border_zero_kernel(unsigned short* __restrict__ yTp)
{
  int n = blockIdx.x, t = threadIdx.x;
  size_t base = (size_t)n * 66 * 66 * 256;
  u16x8 z = (u16x8){0, 0, 0, 0, 0, 0, 0, 0};
  for (int i = t; i < 2112; i += 256) {
    *(u16x8*)(yTp + base + (size_t)i * 8) = z;
    *(u16x8*)(yTp + base + (size_t)65 * 66 * 256 + (size_t)i * 8) = z;
  }
  for (int i = t; i < 2048; i += 256) {
    int hh = 1 + (i >> 5);
    int off = (i & 31) * 8;
    *(u16x8*)(yTp + base + ((size_t)hh * 66 + 0) * 256 + off) = z;
    *(u16x8*)(yTp + base + ((size_t)hh * 66 + 65) * 256 + off) = z;
  }
}

// ---------------------------------------------------------------------------
// K2: y (fp32 NCHW) -> zero-padded bf16 NHWC yTp[n][hh][ww][c]
__global__ __launch_bounds__(256) void transpose_pad_kernel(
    const float* __restrict__ y, unsigned short* __restrict__ yTp)
{
  __shared__ unsigned short T[64][68];   // [c_local][w]
  int t = threadIdx.x;
  int nb = blockIdx.x; int n = nb >> 6, h = nb & 63;
  int w4 = (t & 15) * 4;
  int cl = t >> 4;
  for (int cb = 0; cb < 4; ++cb) {
    __syncthreads();
    #pragma unroll
    for (int r = 0; r < 4; ++r) {
      int c = cb * 64 + cl + r * 16;
      float4 v = *(const float4*)(y + ((((size_t)n * 256 + c) * 64 + h) << 6) + w4);
      u16x4 pv = { f2bf(v.x), f2bf(v.y), f2bf(v.z), f2bf(v.w) };
      *(u16x4*)&T[cl + r * 16][w4] = pv;
    }
    __syncthreads();
    size_t base = (((size_t)n * 66 + (h + 1)) * 66 + 1) * 256 + cb * 64;
    #pragma unroll
    for (int pass = 0; pass < 2; ++pass) {
      int w = pass * 32 + (t >> 3);
      int c8 = (t & 7) * 8;
      u16x8 o;
      #pragma unroll
      for (int i = 0; i < 8; ++i) o[i] = T[c8 + i][w];
      *(u16x8*)(yTp + base + (size_t)w * 256 + c8) = o;
    }
  }
}

// ---------------------------------------------------------------------------
// K3: conv3x3 implicit GEMM, 2-phase double-buffered (T3 minimal recipe):
// issue next-iteration stages BEFORE current compute, ONE barrier per iter.
// LDS: A dbuf 2x16.5KB + B dbuf 2x16KB = 65 KB -> still 2 blocks/CU.
__global__ __launch_bounds__(256, 2) void conv3x3_mfma_kernel(
    const unsigned short* __restrict__ yTp, const unsigned short* __restrict__ Bt,
    const float* __restrict__ bias1, const float* __restrict__ a1p,
    unsigned short* __restrict__ hT)
{
  __shared__ unsigned short Als[2][4][4][66][8];  // [buf][q][row][px][8ch]
  __shared__ unsigned short Bls[2][4][256][8];    // [buf][q][cout][8ch]
  int tid = threadIdx.x;
  int w = tid >> 6, l = tid & 63;
  int lr = l & 15, quad = l >> 4;
  int wm = w >> 1, wn = w & 1;                 // 2x2 waves over (M=128, N=256)
  int bm = blockIdx.x;                         // 0..511
  int n = bm >> 5, hb = (bm & 31) * 2;

  f32x4 acc[4][8];
  #pragma unroll
  for (int im = 0; im < 4; ++im)
    #pragma unroll
    for (int in_ = 0; in_ < 8; ++in_)
      acc[im][in_] = (f32x4){0.f, 0.f, 0.f, 0.f};

  const size_t nb66 = (size_t)n * 66;
  const unsigned short* gaRow = yTp + (((nb66 + hb + w) * 66) << 8);
  const unsigned short* gb0 = Bt + (size_t)(w * 64 + l) * 2304;

  // A stage: wave w -> padded row hb+w; px 0..63 full-wave async,
  // px 64..65 via 2-lane exec-masked async (VMEM honors EXEC).
  auto stageA = [&](int chunk, int buf) {
    const unsigned short* ga = gaRow + ((size_t)l << 8) + chunk * 32;
    #pragma unroll
    for (int q = 0; q < 4; ++q)
      async_ld16(ga + q * 8, &Als[buf][q][w][0][0]);
    if (l < 2) {
      const unsigned short* ga2 = gaRow + ((size_t)(64 + l) << 8) + chunk * 32;
      #pragma unroll
      for (int q = 0; q < 4; ++q)
        async_ld16(ga2 + q * 8, &Als[buf][q][w][64][0]);
    }
  };
  // B stage: wave w -> couts w*64..w*64+63
  auto stageB = [&](int tap, int chunk, int buf) {
    const unsigned short* gb = gb0 + tap * 256 + chunk * 32;
    #pragma unroll
    for (int q = 0; q < 4; ++q)
      async_ld16(gb + q * 8, &Bls[buf][q][w * 64][0]);
  };

  // prologue: stage (chunk0, tap0)
  stageA(0, 0);
  stageB(0, 0, 0);
  __syncthreads();

  int ab = 0, bb = 0;
  #pragma unroll 1
  for (int c = 0; c < 8; ++c) {
    #pragma unroll 1
    for (int t = 0; t < 9; ++t) {
      // issue NEXT stages first -> latency hides under this iter's MFMAs
      if (t == 0 && c < 7) stageA(c + 1, ab ^ 1);
      if (t < 8) stageB(t + 1, c, bb ^ 1);
      else if (c < 7) stageB(0, c + 1, bb ^ 1);

      int ti = t / 3, tj = t - 3 * ti;
      bf16x8 af[4], bfr[8];
      #pragma unroll
      for (int im = 0; im < 4; ++im)
        af[im] = *(const bf16x8*)&Als[ab][quad][wm + ti][im * 16 + lr + tj][0];
      #pragma unroll
      for (int in_ = 0; in_ < 8; ++in_)
        bfr[in_] = *(const bf16x8*)&Bls[bb][quad][wn * 128 + in_ * 16 + lr][0];
      #pragma unroll
      for (int im = 0; im < 4; ++im)
        #pragma unroll
        for (int in_ = 0; in_ < 8; ++in_)
          acc[im][in_] = __builtin_amdgcn_mfma_f32_16x16x32_bf16(
              af[im], bfr[in_], acc[im][in_], 0, 0, 0);

      __syncthreads();   // drains this iter's stage issues; protects buffer swap
      bb ^= 1;
    }
    ab ^= 1;
  }

  float a1 = a1p[0];
  size_t pix0 = (size_t)bm * 128 + wm * 64;
  #pragma unroll
  for (int in_ = 0; in_ < 8; ++in_) {
    int c = wn * 128 + in_ * 16 + lr;
    float bs = bias1[c];
    #pragma unroll
    for (int im = 0; im < 4; ++im) {
      size_t m0 = pix0 + im * 16 + quad * 4;
      #pragma unroll
      for (int r = 0; r < 4; ++r) {
        float v = acc[im][in_][r] + bs;
        v = (v >= 0.f) ? v : a1 * v;
        hT[(m0 + r) * 256 + c] = f2bf(v);
      }
    }
  }
}

// ---------------------------------------------------------------------------
// K4: 1x1 conv C->9 + BN + PReLU. 4 lanes per pixel, shfl reduce.
__global__ __launch_bounds__(256) void conv1x1_kernel(
    const unsigned short* __restrict__ hT, const float* __restrict__ W2f,
    const float* __restrict__ bias2, const float* __restrict__ a2p,
    float* __restrict__ kernP)
{
  __shared__ float w2s[2304];
  int t = threadIdx.x;
  for (int i = t; i < 2304; i += 256) w2s[i] = W2f[i];
  __syncthreads();
  int seg = t & 3;
  int pr = t >> 2;
  int p = blockIdx.x * 64 + pr;
  const unsigned short* hp = hT + (size_t)p * 256;
  float acc[9];
  #pragma unroll
  for (int j = 0; j < 9; ++j) acc[j] = 0.f;
  for (int c0 = seg * 8; c0 < 256; c0 += 32) {
    u16x8 hv = *(const u16x8*)(hp + c0);
    float hf[8];
    #pragma unroll
    for (int i = 0; i < 8; ++i) hf[i] = bf2f(hv[i]);
    #pragma unroll
    for (int j = 0; j < 9; ++j)
      #pragma unroll
      for (int i = 0; i < 8; ++i)
        acc[j] = fmaf(hf[i], w2s[j * 256 + c0 + i], acc[j]);
  }
  #pragma unroll
  for (int j = 0; j < 9; ++j) {
    acc[j] += __shfl_xor(acc[j], 1);
    acc[j] += __shfl_xor(acc[j], 2);
  }
  if (seg == 0) {
    float a2 = a2p[0];
    #pragma unroll
    for (int j = 0; j < 9; ++j) {
      float v = acc[j] + bias2[j];
      v = (v >= 0.f) ? v : a2 * v;
      kernP[j * 65536 + p] = v;
    }
  }
}

// ---------------------------------------------------------------------------
// K5: scrambled unfold-reshape apply. Each thread's 144 (oi,k2) taps are
// CONSECUTIVE flat indices r: walk a zero-padded 66x67 LDS plane with addr++
// (+3 fixup every 64, single precomputed plane-crossing fixup). No bounds
// checks, no per-tap decode/divide.
__global__ __launch_bounds__(256) void apply_dyn_kernel(
    const float* __restrict__ x, const float* __restrict__ kernP,
    float* __restrict__ out)
{
  __shared__ float xs[66 * 67];   // padded plane, row stride 67
  __shared__ float ks[9][16];
  int t = threadIdx.x;
  int b = blockIdx.x;             // ((n*64 + h')*4 + g)
  int g = b & 3;
  int nh = b >> 2;
  int n = nh >> 6, hp = nh & 63;
  int c = 4 * hp + g;

  const float* xplane = x + (((size_t)n * 256 + c) << 12);
  for (int i = t; i < 1024; i += 256) {
    float4 v = *(const float4*)(xplane + i * 4);
    int row = i >> 4;
    int col = (i & 15) * 4;
    float* d = &xs[(row + 1) * 67 + col + 1];
    d[0] = v.x; d[1] = v.y; d[2] = v.z; d[3] = v.w;
  }
  // zero border: rows 0 & 65 fully; cols 0 & 65 of rows 1..64 (col 66 unused)
  if (t < 67) { xs[t] = 0.f; xs[65 * 67 + t] = 0.f; }
  if (t < 128) { int r = (t >> 1) + 1; int cc = (t & 1) * 65; xs[r * 67 + cc] = 0.f; }
  int pbase = n * 4096 + hp * 64 + g * 16;
  for (int i = t; i < 144; i += 256)
    ks[i / 16][i & 15] = kernP[(i / 16) * 65536 + pbase + (i & 15)];
  __syncthreads();

  int s = t & 15;
  int crow = t >> 4;              // 0..15; this thread: cp = crow*16 + oi
  float ksr[9];
  #pragma unroll
  for (int k2 = 0; k2 < 9; ++k2) ksr[k2] = ks[k2][s];

  // r = s*2304 + cp*9 + k2 : 144 consecutive values starting at r0
  int r0 = s * 2304 + crow * 144;
  int k0 = r0 >> 12;
  int rem0 = r0 & 4095;
  int wcol = rem0 & 63;
  int ti0 = (k0 >= 6) ? 2 : ((k0 >= 3) ? 1 : 0);
  int tj0 = k0 - 3 * ti0;
  // padded addr = (h'+ti)*67 + (w'+tj)
  int addr = (rem0 >> 6) * 67 + wcol + ti0 * 67 + tj0;
  int cnt = 4096 - rem0;          // advances until plane crossing (<=144 fires once)
  int kN = k0 + 1;
  int tiN = (kN >= 6) ? 2 : ((kN >= 3) ? 1 : 0);
  int addrAtCross = tiN * 67 + (kN - 3 * tiN);

  size_t outIdx = (((size_t)n * 256 + crow * 16) << 12) + (hp << 6) + g * 16 + s;
  #pragma unroll 4
  for (int oi = 0; oi < 16; ++oi) {
    float acc = 0.f;
    #pragma unroll
    for (int k2 = 0; k2 < 9; ++k2) {
      acc = fmaf(xs[addr], ksr[k2], acc);
      ++wcol; ++addr;
      if (wcol == 64) { wcol = 0; addr += 3; }   // row step: 67-64+1 = +4 total
      if (--cnt == 0) addr = addrAtCross;        // k-plane crossing (once at most)
    }
    out[outIdx + ((size_t)oi << 12)] = acc;
  }
}

// ---------------------------------------------------------------------------
extern "C" void kernel_launch(void* const* d_in, const int* in_sizes, int n_in,
                              void* d_out, int out_size, void* d_ws, size_t ws_size,
                              hipStream_t stream) {
  const float* x  = (const float*)d_in[0];
  const float* y  = (const float*)d_in[1];
  const float* W1 = (const float*)d_in[2];
  const float* g1 = (const float*)d_in[3];
  const float* b1 = (const float*)d_in[4];
  const float* m1 = (const float*)d_in[5];
  const float* v1 = (const float*)d_in[6];
  const float* a1 = (const float*)d_in[7];
  const float* W2 = (const float*)d_in[8];
  const float* g2 = (const float*)d_in[9];
  const float* b2 = (const float*)d_in[10];
  const float* m2 = (const float*)d_in[11];
  const float* v2 = (const float*)d_in[12];
  const float* a2 = (const float*)d_in[13];
  float* out = (float*)d_out;

  char* ws = (char*)d_ws;
  size_t off = 0;
  const size_t yTp_bytes = (size_t)16 * 66 * 66 * 256 * 2;
  unsigned short* yTp = (unsigned short*)(ws + off); off += yTp_bytes;
  unsigned short* Bt  = (unsigned short*)(ws + off); off += (size_t)589824 * 2;
  unsigned short* hT  = (unsigned short*)(ws + off); off += (size_t)16777216 * 2;
  float* kernP = (float*)(ws + off); off += (size_t)589824 * 4;
  float* bias1 = (float*)(ws + off); off += 1024;
  float* W2f   = (float*)(ws + off); off += 9216;
  float* bias2 = (float*)(ws + off); off += 64;

  params_kernel<<<1, 256, 0, stream>>>(g1, b1, m1, v1, W2, g2, b2, m2, v2,
                                       bias1, W2f, bias2);
  fold_w1_kernel<<<256, 256, 0, stream>>>(W1, g1, v1, Bt);
  border_zero_kernel<<<16, 256, 0, stream>>>(yTp);
  transpose_pad_kernel<<<1024, 256, 0, stream>>>(y, yTp);
  conv3x3_mfma_kernel<<<512, 256, 0, stream>>>(yTp, Bt, bias1, a1, hT);
  conv1x1_kernel<<<1024, 256, 0, stream>>>(hT, W2f, bias2, a2, kernP);
  apply_dyn_kernel<<<4096, 256, 0, stream>>>(x, kernP, out);
}

// Round 2
// 324.459 us; speedup vs baseline: 1.1350x; 1.1350x over previous
//
#include <hip/hip_runtime.h>
#include <hip/hip_bf16.h>

typedef __attribute__((ext_vector_type(8))) short bf16x8;
typedef __attribute__((ext_vector_type(4))) float f32x4;
typedef __attribute__((ext_vector_type(8))) unsigned short u16x8;
typedef __attribute__((ext_vector_type(4))) unsigned short u16x4;

#define BN_EPS 1e-5f

__device__ __forceinline__ unsigned short f2bf(float f) {
  unsigned int u = __float_as_uint(f);
  unsigned int r = u + 0x7FFFu + ((u >> 16) & 1u);
  return (unsigned short)(r >> 16);
}
__device__ __forceinline__ float bf2f(unsigned short u) {
  union { float f; unsigned int i; } v; v.i = ((unsigned int)u) << 16; return v.f;
}

// async global->LDS, 16B per lane. LDS dest = wave-uniform base + lane*16.
__device__ __forceinline__ void async_ld16(const unsigned short* g, unsigned short* l) {
  __builtin_amdgcn_global_load_lds(
      (const __attribute__((address_space(1))) void*)g,
      (__attribute__((address_space(3))) void*)l, 16, 0, 0);
}

// ---------------------------------------------------------------------------
// K0: fold BN params -> bias1[256], W2f[9*256] (scale folded), bias2[9]
__global__ __launch_bounds__(256) void params_kernel(
    const float* __restrict__ g1, const float* __restrict__ b1,
    const float* __restrict__ m1, const float* __restrict__ v1,
    const float* __restrict__ W2, const float* __restrict__ g2,
    const float* __restrict__ b2, const float* __restrict__ m2,
    const float* __restrict__ v2,
    float* __restrict__ bias1, float* __restrict__ W2f, float* __restrict__ bias2)
{
  int t = threadIdx.x;
  {
    float s = g1[t] * rsqrtf(v1[t] + BN_EPS);
    bias1[t] = b1[t] - m1[t] * s;
  }
  for (int i = t; i < 2304; i += 256) {
    int j = i >> 8;
    float s2 = g2[j] * rsqrtf(v2[j] + BN_EPS);
    W2f[i] = W2[i] * s2;
  }
  if (t < 9) {
    float s2 = g2[t] * rsqrtf(v2[t] + BN_EPS);
    bias2[t] = b2[t] - m2[t] * s2;
  }
}

// ---------------------------------------------------------------------------
// K1: fold scale1 into W1, quantize bf16.
// NEW layout: Bt2[tap][chunk(8)][q(4)][cout(256)][8ch] so conv3x3's B staging
// is lane-contiguous (16 B/lane, 1 KB/instr coalesced).
__global__ __launch_bounds__(256) void fold_w1_kernel(
    const float* __restrict__ W1, const float* __restrict__ g1,
    const float* __restrict__ v1, unsigned short* __restrict__ Bt)
{
  int o = blockIdx.x;           // cout 0..255
  int t = threadIdx.x;          // cin 0..255
  float s = g1[o] * rsqrtf(v1[o] + BN_EPS);
  const float* src = W1 + (size_t)o * 2304 + (size_t)t * 9;   // W1[o][cin][tap]
  int chunk = t >> 5, q = (t >> 3) & 3, e = t & 7;
  #pragma unroll
  for (int tap = 0; tap < 9; ++tap) {
    float wv = src[tap] * s;
    Bt[((((size_t)tap * 8 + chunk) * 4 + q) * 256 + o) * 8 + e] = f2bf(wv);
  }
}

// ---------------------------------------------------------------------------
// K1b: zero the pad border of each (n,qg) plane of yTp2[n][qg][66][66][8]
__global__ __launch_bounds__(256) void border_zero_kernel(unsigned short* __restrict__ yTp)
{
  int p = blockIdx.x;           // n*32 + qg, 0..511
  int t = threadIdx.x;
  size_t base = (size_t)p * (66 * 66 * 8);
  u16x8 z = (u16x8){0, 0, 0, 0, 0, 0, 0, 0};
  if (t < 66) {
    *(u16x8*)(yTp + base + (size_t)t * 8) = z;                   // row hh=0
    *(u16x8*)(yTp + base + ((size_t)65 * 66 + t) * 8) = z;       // row hh=65
  }
  if (t >= 128 && t < 192) {
    int hh = t - 127;                                            // 1..64
    *(u16x8*)(yTp + base + ((size_t)hh * 66) * 8) = z;           // col ww=0
    *(u16x8*)(yTp + base + ((size_t)hh * 66 + 65) * 8) = z;      // col ww=65
  }
}

// ---------------------------------------------------------------------------
// K2: y (fp32 NCHW) -> zero-padded bf16 yTp2[n][qg(32)][hh][ww][8ch]
__global__ __launch_bounds__(256) void transpose_pad_kernel(
    const float* __restrict__ y, unsigned short* __restrict__ yTp)
{
  __shared__ unsigned short T[64][68];   // [c_local][w]
  int t = threadIdx.x;
  int nb = blockIdx.x; int n = nb >> 6, h = nb & 63;
  int w4 = (t & 15) * 4;
  int cl = t >> 4;
  for (int cb = 0; cb < 4; ++cb) {
    __syncthreads();
    #pragma unroll
    for (int r = 0; r < 4; ++r) {
      int c = cb * 64 + cl + r * 16;
      float4 v = *(const float4*)(y + ((((size_t)n * 256 + c) * 64 + h) << 6) + w4);
      u16x4 pv = { f2bf(v.x), f2bf(v.y), f2bf(v.z), f2bf(v.w) };
      *(u16x4*)&T[cl + r * 16][w4] = pv;
    }
    __syncthreads();
    // write: plane qg = cb*8 + c8, row h+1, col w+1
    size_t base = ((((size_t)n * 32 + cb * 8) * 66 + (h + 1)) * 66 + 1) * 8;
    #pragma unroll
    for (int pass = 0; pass < 2; ++pass) {
      int w = pass * 32 + (t >> 3);
      int c8 = t & 7;
      u16x8 o;
      #pragma unroll
      for (int i = 0; i < 8; ++i) o[i] = T[c8 * 8 + i][w];
      *(u16x8*)(yTp + base + ((size_t)c8 * (66 * 66) + w) * 8) = o;
    }
  }
}

// ---------------------------------------------------------------------------
// K3: conv3x3 implicit GEMM. Fixes vs prev round:
//  (a) B and A staging fully coalesced (lane-contiguous 16 B via new layouts)
//  (b) stage issued AFTER the barrier -> the drain at the NEXT barrier has a
//      full compute phase (~460 cyc) covering load latency. One barrier/iter.
__global__ __launch_bounds__(256, 2) void conv3x3_mfma_kernel(
    const unsigned short* __restrict__ yTp, const unsigned short* __restrict__ Bt,
    const float* __restrict__ bias1, const float* __restrict__ a1p,
    unsigned short* __restrict__ hT)
{
  __shared__ unsigned short Als[2][4][4][66][8];  // [buf][q][row][px][8ch]
  __shared__ unsigned short Bls[2][4][256][8];    // [buf][q][cout][8ch]
  int tid = threadIdx.x;
  int w = tid >> 6, l = tid & 63;
  int lr = l & 15, quad = l >> 4;
  int wm = w >> 1, wn = w & 1;                 // 2x2 waves over (M=128, N=256)
  int bm = blockIdx.x;                         // 0..511
  int n = bm >> 5, hb = (bm & 31) * 2;

  f32x4 acc[4][8];
  #pragma unroll
  for (int im = 0; im < 4; ++im)
    #pragma unroll
    for (int in_ = 0; in_ < 8; ++in_)
      acc[im][in_] = (f32x4){0.f, 0.f, 0.f, 0.f};

  const unsigned short* gaBase = yTp + (size_t)n * 32 * (66 * 66 * 8);

  // A stage: wave w -> padded row hb+w. Lane-contiguous 16 B (px stride = 16 B).
  auto stageA = [&](int chunk, int buf) {
    int qg0 = chunk * 4;
    #pragma unroll
    for (int q = 0; q < 4; ++q) {
      const unsigned short* ga = gaBase +
          (((size_t)(qg0 + q) * 66 + (hb + w)) * 66 + l) * 8;
      async_ld16(ga, &Als[buf][q][w][0][0]);
    }
    if (l < 2) {  // px 64,65 tail: 2-lane exec-masked async, still contiguous
      #pragma unroll
      for (int q = 0; q < 4; ++q) {
        const unsigned short* ga = gaBase +
            (((size_t)(qg0 + q) * 66 + (hb + w)) * 66 + 64 + l) * 8;
        async_ld16(ga, &Als[buf][q][w][64][0]);
      }
    }
  };
  // B stage: wave w -> couts w*64..w*64+63. Lane-contiguous 16 B.
  auto stageB = [&](int tap, int chunk, int buf) {
    #pragma unroll
    for (int q = 0; q < 4; ++q) {
      const unsigned short* gb = Bt +
          ((((size_t)tap * 8 + chunk) * 4 + q) * 256 + w * 64 + l) * 8;
      async_ld16(gb, &Bls[buf][q][w * 64][0]);
    }
  };

  // prologue: stage (chunk0, tap0); first barrier drains it (once, uncovered)
  stageA(0, 0);
  stageB(0, 0, 0);

  int ab = 0, bb = 0;
  #pragma unroll 1
  for (int c = 0; c < 8; ++c) {
    #pragma unroll 1
    for (int t = 0; t < 9; ++t) {
      __syncthreads();   // drains stage issued LAST iter (full compute cover);
                         // also: all waves done reading buf^1 -> safe to overwrite
      if (t < 8) stageB(t + 1, c, bb ^ 1);
      else if (c < 7) stageB(0, c + 1, bb ^ 1);
      if (t == 0 && c < 7) stageA(c + 1, ab ^ 1);

      int ti = t / 3, tj = t - 3 * ti;
      bf16x8 af[4], bfr[8];
      #pragma unroll
      for (int im = 0; im < 4; ++im)
        af[im] = *(const bf16x8*)&Als[ab][quad][wm + ti][im * 16 + lr + tj][0];
      #pragma unroll
      for (int in_ = 0; in_ < 8; ++in_)
        bfr[in_] = *(const bf16x8*)&Bls[bb][quad][wn * 128 + in_ * 16 + lr][0];
      #pragma unroll
      for (int im = 0; im < 4; ++im)
        #pragma unroll
        for (int in_ = 0; in_ < 8; ++in_)
          acc[im][in_] = __builtin_amdgcn_mfma_f32_16x16x32_bf16(
              af[im], bfr[in_], acc[im][in_], 0, 0, 0);

      bb ^= 1;
    }
    ab ^= 1;
  }

  float a1 = a1p[0];
  size_t pix0 = (size_t)bm * 128 + wm * 64;
  #pragma unroll
  for (int in_ = 0; in_ < 8; ++in_) {
    int c = wn * 128 + in_ * 16 + lr;
    float bs = bias1[c];
    #pragma unroll
    for (int im = 0; im < 4; ++im) {
      size_t m0 = pix0 + im * 16 + quad * 4;
      #pragma unroll
      for (int r = 0; r < 4; ++r) {
        float v = acc[im][in_][r] + bs;
        v = (v >= 0.f) ? v : a1 * v;
        hT[(m0 + r) * 256 + c] = f2bf(v);
      }
    }
  }
}

// ---------------------------------------------------------------------------
// K4: 1x1 conv C->9 + BN + PReLU. 4 lanes per pixel, shfl reduce.
__global__ __launch_bounds__(256) void conv1x1_kernel(
    const unsigned short* __restrict__ hT, const float* __restrict__ W2f,
    const float* __restrict__ bias2, const float* __restrict__ a2p,
    float* __restrict__ kernP)
{
  __shared__ float w2s[2304];
  int t = threadIdx.x;
  for (int i = t; i < 2304; i += 256) w2s[i] = W2f[i];
  __syncthreads();
  int seg = t & 3;
  int pr = t >> 2;
  int p = blockIdx.x * 64 + pr;
  const unsigned short* hp = hT + (size_t)p * 256;
  float acc[9];
  #pragma unroll
  for (int j = 0; j < 9; ++j) acc[j] = 0.f;
  for (int c0 = seg * 8; c0 < 256; c0 += 32) {
    u16x8 hv = *(const u16x8*)(hp + c0);
    float hf[8];
    #pragma unroll
    for (int i = 0; i < 8; ++i) hf[i] = bf2f(hv[i]);
    #pragma unroll
    for (int j = 0; j < 9; ++j)
      #pragma unroll
      for (int i = 0; i < 8; ++i)
        acc[j] = fmaf(hf[i], w2s[j * 256 + c0 + i], acc[j]);
  }
  #pragma unroll
  for (int j = 0; j < 9; ++j) {
    acc[j] += __shfl_xor(acc[j], 1);
    acc[j] += __shfl_xor(acc[j], 2);
  }
  if (seg == 0) {
    float a2 = a2p[0];
    #pragma unroll
    for (int j = 0; j < 9; ++j) {
      float v = acc[j] + bias2[j];
      v = (v >= 0.f) ? v : a2 * v;
      kernP[j * 65536 + p] = v;
    }
  }
}

// ---------------------------------------------------------------------------
// K5: scrambled unfold-reshape apply: consecutive-r walk over a padded
// 66x67 LDS plane (addr++, +3 fixup every 64, one plane-crossing fixup).
__global__ __launch_bounds__(256) void apply_dyn_kernel(
    const float* __restrict__ x, const float* __restrict__ kernP,
    float* __restrict__ out)
{
  __shared__ float xs[66 * 67];   // padded plane, row stride 67
  __shared__ float ks[9][16];
  int t = threadIdx.x;
  int b = blockIdx.x;             // ((n*64 + h')*4 + g)
  int g = b & 3;
  int nh = b >> 2;
  int n = nh >> 6, hp = nh & 63;
  int c = 4 * hp + g;

  const float* xplane = x + (((size_t)n * 256 + c) << 12);
  for (int i = t; i < 1024; i += 256) {
    float4 v = *(const float4*)(xplane + i * 4);
    int row = i >> 4;
    int col = (i & 15) * 4;
    float* d = &xs[(row + 1) * 67 + col + 1];
    d[0] = v.x; d[1] = v.y; d[2] = v.z; d[3] = v.w;
  }
  if (t < 67) { xs[t] = 0.f; xs[65 * 67 + t] = 0.f; }
  if (t < 128) { int r = (t >> 1) + 1; int cc = (t & 1) * 65; xs[r * 67 + cc] = 0.f; }
  int pbase = n * 4096 + hp * 64 + g * 16;
  for (int i = t; i < 144; i += 256)
    ks[i / 16][i & 15] = kernP[(i / 16) * 65536 + pbase + (i & 15)];
  __syncthreads();

  int s = t & 15;
  int crow = t >> 4;              // 0..15; this thread: cp = crow*16 + oi
  float ksr[9];
  #pragma unroll
  for (int k2 = 0; k2 < 9; ++k2) ksr[k2] = ks[k2][s];

  int r0 = s * 2304 + crow * 144;
  int k0 = r0 >> 12;
  int rem0 = r0 & 4095;
  int wcol = rem0 & 63;
  int ti0 = (k0 >= 6) ? 2 : ((k0 >= 3) ? 1 : 0);
  int tj0 = k0 - 3 * ti0;
  int addr = (rem0 >> 6) * 67 + wcol + ti0 * 67 + tj0;
  int cnt = 4096 - rem0;
  int kN = k0 + 1;
  int tiN = (kN >= 6) ? 2 : ((kN >= 3) ? 1 : 0);
  int addrAtCross = tiN * 67 + (kN - 3 * tiN);

  size_t outIdx = (((size_t)n * 256 + crow * 16) << 12) + (hp << 6) + g * 16 + s;
  #pragma unroll 4
  for (int oi = 0; oi < 16; ++oi) {
    float acc = 0.f;
    #pragma unroll
    for (int k2 = 0; k2 < 9; ++k2) {
      acc = fmaf(xs[addr], ksr[k2], acc);
      ++wcol; ++addr;
      if (wcol == 64) { wcol = 0; addr += 3; }
      if (--cnt == 0) addr = addrAtCross;
    }
    out[outIdx + ((size_t)oi << 12)] = acc;
  }
}

// ---------------------------------------------------------------------------
extern "C" void kernel_launch(void* const* d_in, const int* in_sizes, int n_in,
                              void* d_out, int out_size, void* d_ws, size_t ws_size,
                              hipStream_t stream) {
  const float* x  = (const float*)d_in[0];
  const float* y  = (const float*)d_in[1];
  const float* W1 = (const float*)d_in[2];
  const float* g1 = (const float*)d_in[3];
  const float* b1 = (const float*)d_in[4];
  const float* m1 = (const float*)d_in[5];
  const float* v1 = (const float*)d_in[6];
  const float* a1 = (const float*)d_in[7];
  const float* W2 = (const float*)d_in[8];
  const float* g2 = (const float*)d_in[9];
  const float* b2 = (const float*)d_in[10];
  const float* m2 = (const float*)d_in[11];
  const float* v2 = (const float*)d_in[12];
  const float* a2 = (const float*)d_in[13];
  float* out = (float*)d_out;

  char* ws = (char*)d_ws;
  size_t off = 0;
  const size_t yTp_bytes = (size_t)16 * 66 * 66 * 256 * 2;
  unsigned short* yTp = (unsigned short*)(ws + off); off += yTp_bytes;
  unsigned short* Bt  = (unsigned short*)(ws + off); off += (size_t)589824 * 2;
  unsigned short* hT  = (unsigned short*)(ws + off); off += (size_t)16777216 * 2;
  float* kernP = (float*)(ws + off); off += (size_t)589824 * 4;
  float* bias1 = (float*)(ws + off); off += 1024;
  float* W2f   = (float*)(ws + off); off += 9216;
  float* bias2 = (float*)(ws + off); off += 64;

  params_kernel<<<1, 256, 0, stream>>>(g1, b1, m1, v1, W2, g2, b2, m2, v2,
                                       bias1, W2f, bias2);
  fold_w1_kernel<<<256, 256, 0, stream>>>(W1, g1, v1, Bt);
  border_zero_kernel<<<512, 256, 0, stream>>>(yTp);
  transpose_pad_kernel<<<1024, 256, 0, stream>>>(y, yTp);
  conv3x3_mfma_kernel<<<512, 256, 0, stream>>>(yTp, Bt, bias1, a1, hT);
  conv1x1_kernel<<<1024, 256, 0, stream>>>(hT, W2f, bias2, a2, kernP);
  apply_dyn_kernel<<<4096, 256, 0, stream>>>(x, kernP, out);
}

// Round 3
// 310.422 us; speedup vs baseline: 1.1863x; 1.0452x over previous
//
#include <hip/hip_runtime.h>
#include <hip/hip_bf16.h>

typedef __attribute__((ext_vector_type(8))) short bf16x8;
typedef __attribute__((ext_vector_type(4))) float f32x4;
typedef __attribute__((ext_vector_type(8))) unsigned short u16x8;
typedef __attribute__((ext_vector_type(4))) unsigned short u16x4;

#define BN_EPS 1e-5f

__device__ __forceinline__ unsigned short f2bf(float f) {
  unsigned int u = __float_as_uint(f);
  unsigned int r = u + 0x7FFFu + ((u >> 16) & 1u);
  return (unsigned short)(r >> 16);
}
__device__ __forceinline__ float bf2f(unsigned short u) {
  union { float f; unsigned int i; } v; v.i = ((unsigned int)u) << 16; return v.f;
}

// async global->LDS, 16B per lane. LDS dest = wave-uniform base + lane*16.
__device__ __forceinline__ void async_ld16(const unsigned short* g, unsigned short* l) {
  __builtin_amdgcn_global_load_lds(
      (const __attribute__((address_space(1))) void*)g,
      (__attribute__((address_space(3))) void*)l, 16, 0, 0);
}

// ---------------------------------------------------------------------------
// K1: fold scale1 into W1 (bf16, staged layout) + all BN param folding.
// Layout: Bt[tap][chunk(8)][q(4)][cout(256)][8ch] -> conv3x3 B staging is
// lane-contiguous (16 B/lane, 1 KB/instr coalesced).
__global__ __launch_bounds__(256) void fold_w1_kernel(
    const float* __restrict__ W1, const float* __restrict__ g1,
    const float* __restrict__ b1, const float* __restrict__ m1,
    const float* __restrict__ v1, const float* __restrict__ W2,
    const float* __restrict__ g2, const float* __restrict__ b2,
    const float* __restrict__ m2, const float* __restrict__ v2,
    unsigned short* __restrict__ Bt, float* __restrict__ bias1,
    float* __restrict__ W2f, float* __restrict__ bias2)
{
  int o = blockIdx.x;           // cout 0..255
  int t = threadIdx.x;          // cin 0..255
  if (o == 0) {                 // merged params work (once)
    float s1 = g1[t] * rsqrtf(v1[t] + BN_EPS);
    bias1[t] = b1[t] - m1[t] * s1;
    for (int i = t; i < 2304; i += 256) {
      int j = i >> 8;
      float s2 = g2[j] * rsqrtf(v2[j] + BN_EPS);
      W2f[i] = W2[i] * s2;
    }
    if (t < 9) {
      float s2 = g2[t] * rsqrtf(v2[t] + BN_EPS);
      bias2[t] = b2[t] - m2[t] * s2;
    }
  }
  float s = g1[o] * rsqrtf(v1[o] + BN_EPS);
  const float* src = W1 + (size_t)o * 2304 + (size_t)t * 9;   // W1[o][cin][tap]
  int chunk = t >> 5, q = (t >> 3) & 3, e = t & 7;
  #pragma unroll
  for (int tap = 0; tap < 9; ++tap) {
    float wv = src[tap] * s;
    Bt[((((size_t)tap * 8 + chunk) * 4 + q) * 256 + o) * 8 + e] = f2bf(wv);
  }
}

// ---------------------------------------------------------------------------
// K2: y (fp32 NCHW) -> zero-padded bf16 yTp[n][qg(32)][hh][ww][8ch]
// Border zeroing merged in (disjoint regions per block; h==0 blocks do rows).
__global__ __launch_bounds__(256) void transpose_pad_kernel(
    const float* __restrict__ y, unsigned short* __restrict__ yTp)
{
  __shared__ unsigned short T[64][68];   // [c_local][w]
  int t = threadIdx.x;
  int nb = blockIdx.x; int n = nb >> 6, h = nb & 63;
  int w4 = (t & 15) * 4;
  int cl = t >> 4;
  for (int cb = 0; cb < 4; ++cb) {
    __syncthreads();
    #pragma unroll
    for (int r = 0; r < 4; ++r) {
      int c = cb * 64 + cl + r * 16;
      float4 v = *(const float4*)(y + ((((size_t)n * 256 + c) * 64 + h) << 6) + w4);
      u16x4 pv = { f2bf(v.x), f2bf(v.y), f2bf(v.z), f2bf(v.w) };
      *(u16x4*)&T[cl + r * 16][w4] = pv;
    }
    __syncthreads();
    size_t base = ((((size_t)n * 32 + cb * 8) * 66 + (h + 1)) * 66 + 1) * 8;
    #pragma unroll
    for (int pass = 0; pass < 2; ++pass) {
      int w = pass * 32 + (t >> 3);
      int c8 = t & 7;
      u16x8 o;
      #pragma unroll
      for (int i = 0; i < 8; ++i) o[i] = T[c8 * 8 + i][w];
      *(u16x8*)(yTp + base + ((size_t)c8 * (66 * 66) + w) * 8) = o;
    }
  }
  // ---- merged border zeroing (global, disjoint, no sync needed) ----
  u16x8 z = (u16x8){0, 0, 0, 0, 0, 0, 0, 0};
  size_t nb32 = (size_t)n * 32;
  if (t < 64) {                       // cols ww=0 / ww=65 of row h+1, 32 planes
    int qg = t & 31, side = t >> 5;
    *(u16x8*)(yTp + (((nb32 + qg) * 66 + (h + 1)) * 66 + side * 65) * 8) = z;
  }
  if (h == 0) {                       // rows hh=0 and hh=65, all planes/cols
    for (int i = t; i < 2112; i += 256) {   // 32 planes * 66 cols
      int qg = i / 66, ww = i - qg * 66;
      *(u16x8*)(yTp + (((nb32 + qg) * 66 + 0) * 66 + ww) * 8) = z;
      *(u16x8*)(yTp + (((nb32 + qg) * 66 + 65) * 66 + ww) * 8) = z;
    }
  }
}

// ---------------------------------------------------------------------------
// K3: conv3x3 implicit GEMM + FUSED 1x1 conv epilogue.
// Changes vs prev: taps fully unrolled (chunk unroll x2) so ti/tj/buffer
// indices are compile-time -> LDS addrs become base+immediate; setprio(1)
// around MFMA cluster; conv1x1 runs block-locally from an LDS h-tile
// (union-overlaid on staging buffers) -> hT global round-trip eliminated.
__global__ __launch_bounds__(256, 2) void conv3x3_mfma_kernel(
    const unsigned short* __restrict__ yTp, const unsigned short* __restrict__ Bt,
    const float* __restrict__ bias1, const float* __restrict__ a1p,
    const float* __restrict__ W2f, const float* __restrict__ bias2,
    const float* __restrict__ a2p, float* __restrict__ kernP)
{
  __shared__ union SM {
    struct { unsigned short A[2][4][4][66][8];      // 33792 B
             unsigned short B[2][4][256][8]; } m;   // 32768 B
    unsigned short h[128][264];                     // 67584 B (overlay)
  } sm;
  __shared__ float w2s[2304];

  int tid = threadIdx.x;
  int w = tid >> 6, l = tid & 63;
  int lr = l & 15, quad = l >> 4;
  int wm = w >> 1, wn = w & 1;                 // 2x2 waves over (M=128, N=256)
  int bm = blockIdx.x;                         // 0..511
  int n = bm >> 5, hb = (bm & 31) * 2;

  for (int i = tid; i < 2304; i += 256) w2s[i] = W2f[i];

  f32x4 acc[4][8];
  #pragma unroll
  for (int im = 0; im < 4; ++im)
    #pragma unroll
    for (int in_ = 0; in_ < 8; ++in_)
      acc[im][in_] = (f32x4){0.f, 0.f, 0.f, 0.f};

  const unsigned short* gaBase = yTp + (size_t)n * 32 * (66 * 66 * 8);
  const unsigned short* gaW  = gaBase + ((size_t)(hb + w) * 66 + l) * 8;
  const unsigned short* gaW2 = gaBase + ((size_t)(hb + w) * 66 + 64 + l) * 8;
  const unsigned short* gbW  = Bt + (size_t)(w * 64 + l) * 8;

  auto stageA = [&](int chunk, int buf) {
    #pragma unroll
    for (int q = 0; q < 4; ++q)
      async_ld16(gaW + (size_t)(chunk * 4 + q) * (66 * 66 * 8),
                 &sm.m.A[buf][q][w][0][0]);
    if (l < 2) {
      #pragma unroll
      for (int q = 0; q < 4; ++q)
        async_ld16(gaW2 + (size_t)(chunk * 4 + q) * (66 * 66 * 8),
                   &sm.m.A[buf][q][w][64][0]);
    }
  };
  auto stageB = [&](int tap, int chunk, int buf) {
    const unsigned short* gb = gbW + (size_t)tap * 65536 + (size_t)chunk * 8192;
    #pragma unroll
    for (int q = 0; q < 4; ++q)
      async_ld16(gb + q * 2048, &sm.m.B[buf][q][w * 64][0]);
  };

  // prologue: stage (chunk0, tap0); first barrier drains it (once, uncovered)
  stageA(0, 0);
  stageB(0, 0, 0);

  for (int cc = 0; cc < 8; cc += 2) {
    #pragma unroll
    for (int u = 0; u < 2; ++u) {          // ab = u (compile-time)
      #pragma unroll
      for (int t = 0; t < 9; ++t) {        // bb = (u+t)&1 (compile-time)
        __syncthreads();   // drains stage issued LAST iter (full compute cover)
        int c = cc + u;
        if (t < 8) stageB(t + 1, c, (u + t + 1) & 1);
        else if (c < 7) stageB(0, c + 1, (u + t + 1) & 1);
        if (t == 0 && c < 7) stageA(c + 1, u ^ 1);

        const int ti = t / 3, tj = t % 3;  // fold to constants
        bf16x8 af[4], bfr[8];
        #pragma unroll
        for (int im = 0; im < 4; ++im)
          af[im] = *(const bf16x8*)&sm.m.A[u][quad][wm + ti][im * 16 + lr + tj][0];
        #pragma unroll
        for (int in_ = 0; in_ < 8; ++in_)
          bfr[in_] = *(const bf16x8*)&sm.m.B[(u + t) & 1][quad][wn * 128 + in_ * 16 + lr][0];
        __builtin_amdgcn_s_setprio(1);
        #pragma unroll
        for (int im = 0; im < 4; ++im)
          #pragma unroll
          for (int in_ = 0; in_ < 8; ++in_)
            acc[im][in_] = __builtin_amdgcn_mfma_f32_16x16x32_bf16(
                af[im], bfr[in_], acc[im][in_], 0, 0, 0);
        __builtin_amdgcn_s_setprio(0);
      }
    }
  }

  __syncthreads();            // all staging-buffer reads done -> overlay safe

  // epilogue 1: h = prelu(acc + bias1) -> LDS bf16 tile [pixel][channel]
  float a1 = a1p[0];
  #pragma unroll
  for (int in_ = 0; in_ < 8; ++in_) {
    int cch = wn * 128 + in_ * 16 + lr;
    float bs = bias1[cch];
    #pragma unroll
    for (int im = 0; im < 4; ++im) {
      int p0 = wm * 64 + im * 16 + quad * 4;
      #pragma unroll
      for (int r = 0; r < 4; ++r) {
        float v = acc[im][in_][r] + bs;
        v = (v >= 0.f) ? v : a1 * v;
        sm.h[p0 + r][cch] = f2bf(v);
      }
    }
  }
  __syncthreads();

  // epilogue 2: 1x1 conv C->9 + BN + PReLU, block-local (4 lanes/pixel)
  float a2 = a2p[0];
  int seg = tid & 3, pr = tid >> 2;
  float b2r[9];
  #pragma unroll
  for (int j = 0; j < 9; ++j) b2r[j] = bias2[j];
  #pragma unroll
  for (int rd = 0; rd < 2; ++rd) {
    int pl = rd * 64 + pr;
    float acc2[9];
    #pragma unroll
    for (int j = 0; j < 9; ++j) acc2[j] = 0.f;
    #pragma unroll
    for (int k = 0; k < 8; ++k) {
      int c0 = seg * 8 + k * 32;
      u16x8 hv = *(const u16x8*)&sm.h[pl][c0];
      float hf[8];
      #pragma unroll
      for (int i = 0; i < 8; ++i) hf[i] = bf2f(hv[i]);
      #pragma unroll
      for (int j = 0; j < 9; ++j)
        #pragma unroll
        for (int i = 0; i < 8; ++i)
          acc2[j] = fmaf(hf[i], w2s[j * 256 + c0 + i], acc2[j]);
    }
    #pragma unroll
    for (int j = 0; j < 9; ++j) {
      acc2[j] += __shfl_xor(acc2[j], 1);
      acc2[j] += __shfl_xor(acc2[j], 2);
    }
    if (seg == 0) {
      size_t gp = (size_t)bm * 128 + pl;
      #pragma unroll
      for (int j = 0; j < 9; ++j) {
        float v = acc2[j] + b2r[j];
        v = (v >= 0.f) ? v : a2 * v;
        kernP[j * 65536 + gp] = v;
      }
    }
  }
}

// ---------------------------------------------------------------------------
// K5: scrambled unfold-reshape apply: consecutive-r walk over a padded
// 66x67 LDS plane (addr++, +3 fixup every 64, one plane-crossing fixup).
__global__ __launch_bounds__(256) void apply_dyn_kernel(
    const float* __restrict__ x, const float* __restrict__ kernP,
    float* __restrict__ out)
{
  __shared__ float xs[66 * 67];   // padded plane, row stride 67
  __shared__ float ks[9][16];
  int t = threadIdx.x;
  int b = blockIdx.x;             // ((n*64 + h')*4 + g)
  int g = b & 3;
  int nh = b >> 2;
  int n = nh >> 6, hp = nh & 63;
  int c = 4 * hp + g;

  const float* xplane = x + (((size_t)n * 256 + c) << 12);
  for (int i = t; i < 1024; i += 256) {
    float4 v = *(const float4*)(xplane + i * 4);
    int row = i >> 4;
    int col = (i & 15) * 4;
    float* d = &xs[(row + 1) * 67 + col + 1];
    d[0] = v.x; d[1] = v.y; d[2] = v.z; d[3] = v.w;
  }
  if (t < 67) { xs[t] = 0.f; xs[65 * 67 + t] = 0.f; }
  if (t < 128) { int r = (t >> 1) + 1; int cc = (t & 1) * 65; xs[r * 67 + cc] = 0.f; }
  int pbase = n * 4096 + hp * 64 + g * 16;
  for (int i = t; i < 144; i += 256)
    ks[i / 16][i & 15] = kernP[(i / 16) * 65536 + pbase + (i & 15)];
  __syncthreads();

  int s = t & 15;
  int crow = t >> 4;              // 0..15; this thread: cp = crow*16 + oi
  float ksr[9];
  #pragma unroll
  for (int k2 = 0; k2 < 9; ++k2) ksr[k2] = ks[k2][s];

  int r0 = s * 2304 + crow * 144;
  int k0 = r0 >> 12;
  int rem0 = r0 & 4095;
  int wcol = rem0 & 63;
  int ti0 = (k0 >= 6) ? 2 : ((k0 >= 3) ? 1 : 0);
  int tj0 = k0 - 3 * ti0;
  int addr = (rem0 >> 6) * 67 + wcol + ti0 * 67 + tj0;
  int cnt = 4096 - rem0;
  int kN = k0 + 1;
  int tiN = (kN >= 6) ? 2 : ((kN >= 3) ? 1 : 0);
  int addrAtCross = tiN * 67 + (kN - 3 * tiN);

  size_t outIdx = (((size_t)n * 256 + crow * 16) << 12) + (hp << 6) + g * 16 + s;
  #pragma unroll 4
  for (int oi = 0; oi < 16; ++oi) {
    float acc = 0.f;
    #pragma unroll
    for (int k2 = 0; k2 < 9; ++k2) {
      acc = fmaf(xs[addr], ksr[k2], acc);
      ++wcol; ++addr;
      if (wcol == 64) { wcol = 0; addr += 3; }
      if (--cnt == 0) addr = addrAtCross;
    }
    out[outIdx + ((size_t)oi << 12)] = acc;
  }
}

// ---------------------------------------------------------------------------
extern "C" void kernel_launch(void* const* d_in, const int* in_sizes, int n_in,
                              void* d_out, int out_size, void* d_ws, size_t ws_size,
                              hipStream_t stream) {
  const float* x  = (const float*)d_in[0];
  const float* y  = (const float*)d_in[1];
  const float* W1 = (const float*)d_in[2];
  const float* g1 = (const float*)d_in[3];
  const float* b1 = (const float*)d_in[4];
  const float* m1 = (const float*)d_in[5];
  const float* v1 = (const float*)d_in[6];
  const float* a1 = (const float*)d_in[7];
  const float* W2 = (const float*)d_in[8];
  const float* g2 = (const float*)d_in[9];
  const float* b2 = (const float*)d_in[10];
  const float* m2 = (const float*)d_in[11];
  const float* v2 = (const float*)d_in[12];
  const float* a2 = (const float*)d_in[13];
  float* out = (float*)d_out;

  char* ws = (char*)d_ws;
  size_t off = 0;
  const size_t yTp_bytes = (size_t)16 * 66 * 66 * 256 * 2;
  unsigned short* yTp = (unsigned short*)(ws + off); off += yTp_bytes;
  unsigned short* Bt  = (unsigned short*)(ws + off); off += (size_t)589824 * 2;
  float* kernP = (float*)(ws + off); off += (size_t)589824 * 4;
  float* bias1 = (float*)(ws + off); off += 1024;
  float* W2f   = (float*)(ws + off); off += 9216;
  float* bias2 = (float*)(ws + off); off += 64;

  fold_w1_kernel<<<256, 256, 0, stream>>>(W1, g1, b1, m1, v1, W2, g2, b2, m2, v2,
                                          Bt, bias1, W2f, bias2);
  transpose_pad_kernel<<<1024, 256, 0, stream>>>(y, yTp);
  conv3x3_mfma_kernel<<<512, 256, 0, stream>>>(yTp, Bt, bias1, a1,
                                               W2f, bias2, a2, kernP);
  apply_dyn_kernel<<<4096, 256, 0, stream>>>(x, kernP, out);
}